// Round 12
// baseline (4597.306 us; speedup 1.0000x reference)
//
#include <hip/hip_runtime.h>
#include <hip/hip_bf16.h>

typedef __hip_bfloat16 bf16;
typedef __attribute__((ext_vector_type(8))) short bf16x8;
typedef __attribute__((ext_vector_type(4))) float f32x4;

#define GLDS16(g, l)                                                  \
  __builtin_amdgcn_global_load_lds(                                   \
      (const __attribute__((address_space(1))) void*)(g),             \
      (__attribute__((address_space(3))) void*)(l), 16, 0, 0)

__device__ __forceinline__ float bf2f(bf16 v) { return __bfloat162float(v); }
__device__ __forceinline__ short f2bf(float f) {
  bf16 b = __float2bfloat16(f);
  return *reinterpret_cast<short*>(&b);
}

// Proven agent-scope primitives (R6): the cross-block sync/store mechanism.
__device__ __forceinline__ void ast32(void* p, unsigned v) {
  __hip_atomic_store((unsigned*)p, v, __ATOMIC_RELAXED,
                     __HIP_MEMORY_SCOPE_AGENT);
}
__device__ __forceinline__ unsigned ald32(const void* p) {
  return __hip_atomic_load((const unsigned*)p, __ATOMIC_RELAXED,
                           __HIP_MEMORY_SCOPE_AGENT);
}

// ---------------------------------------------------------------------------
// f32 -> bf16 linear conversion, 8 elems/thread
// ---------------------------------------------------------------------------
__global__ __launch_bounds__(256) void cvt_bf16(const float* __restrict__ in,
                                                bf16* __restrict__ out, int n) {
  const int i = (blockIdx.x * 256 + threadIdx.x) * 8;
  if (i >= n) return;
  const float4 u = *(const float4*)(in + i);
  const float4 v = *(const float4*)(in + i + 4);
  bf16x8 w;
  w[0] = f2bf(u.x); w[1] = f2bf(u.y); w[2] = f2bf(u.z); w[3] = f2bf(u.w);
  w[4] = f2bf(v.x); w[5] = f2bf(v.y); w[6] = f2bf(v.z); w[7] = f2bf(v.w);
  *(bf16x8*)(out + i) = w;
}

// ---------------------------------------------------------------------------
// Wh (f32, [3072][1024] per dir) -> bf16 in MFMA B-fragment order:
// Whb[dir][cg(64)][gate(3)][kk(32)][lane(64)][8]
// ---------------------------------------------------------------------------
__global__ __launch_bounds__(256) void cvt_whb(const float* __restrict__ Wh_f,
                                               const float* __restrict__ Wh_r,
                                               bf16* __restrict__ Whb) {
  const int t = blockIdx.x * 256 + threadIdx.x;  // 786432 threads
  const int d = t / 393216;
  int r = t % 393216;
  const int cg = r / 6144;  r %= 6144;
  const int g = r / 2048;   r %= 2048;
  const int kk = r / 64;
  const int lane = r & 63;
  const float* Wh = d ? Wh_r : Wh_f;
  const int row = g * 1024 + cg * 16 + (lane & 15);
  const int col = kk * 32 + (lane >> 4) * 8;
  const float* s = Wh + (size_t)row * 1024 + col;
  const float4 u = *(const float4*)s;
  const float4 v = *(const float4*)(s + 4);
  bf16x8 w;
  w[0] = f2bf(u.x); w[1] = f2bf(u.y); w[2] = f2bf(u.z); w[3] = f2bf(u.w);
  w[4] = f2bf(v.x); w[5] = f2bf(v.y); w[6] = f2bf(v.z); w[7] = f2bf(v.w);
  *(bf16x8*)(Whb + (size_t)t * 8) = w;
}

// ---------------------------------------------------------------------------
// Prologue: Gi[32768][3072] = X(f32) @ Wib^T + bi  (A reg-staged f32->bf16,
// B bf16 via global_load_lds). 128x128 tile, BK=32, 4 waves.
// ---------------------------------------------------------------------------
__global__ __launch_bounds__(256) void gi_gemm(const float* __restrict__ X,
                                               const bf16* __restrict__ Wi,
                                               const float* __restrict__ bi,
                                               bf16* __restrict__ Gi) {
  __shared__ bf16 As[128 * 32];
  __shared__ bf16 Bs[128 * 32];
  const int tid = threadIdx.x;
  const int lane = tid & 63;
  const int w = tid >> 6;
  const int wm = w >> 1, wn = w & 1;
  const int m0 = blockIdx.y * 128;
  const int n0 = blockIdx.x * 128;
  const int rA = lane & 15;
  const int kl = (lane >> 4) * 8;

  f32x4 acc[4][4] = {};

  const float* Ab = X + (size_t)m0 * 1024;
  const bf16* Bb = Wi + (size_t)n0 * 1024;

  const int arow = tid >> 2;
  const int akk = (tid & 3) * 8;

  for (int kt = 0; kt < 1024; kt += 32) {
    // B: async bf16 global->LDS
#pragma unroll
    for (int i = 0; i < 2; ++i)
      GLDS16(Bb + (size_t)(i * 64 + arow) * 1024 + kt + akk,
             Bs + (i * 256 + w * 64) * 8);
    // A: f32 reg-stage + convert
#pragma unroll
    for (int i = 0; i < 2; ++i) {
      const int c = i * 256 + tid;
      const int row = c >> 2;
      const int kk = (c & 3) * 8;
      const float* sa = Ab + (size_t)row * 1024 + kt + kk;
      const float4 a0 = *(const float4*)sa;
      const float4 a1 = *(const float4*)(sa + 4);
      bf16x8 av;
      av[0] = f2bf(a0.x); av[1] = f2bf(a0.y); av[2] = f2bf(a0.z); av[3] = f2bf(a0.w);
      av[4] = f2bf(a1.x); av[5] = f2bf(a1.y); av[6] = f2bf(a1.z); av[7] = f2bf(a1.w);
      *(bf16x8*)(As + c * 8) = av;
    }
    asm volatile("s_waitcnt vmcnt(0)" ::: "memory");
    __syncthreads();

    bf16x8 a[4], b[4];
#pragma unroll
    for (int f = 0; f < 4; ++f) {
      a[f] = *(const bf16x8*)(As + (wm * 64 + f * 16 + rA) * 32 + kl);
      b[f] = *(const bf16x8*)(Bs + (wn * 64 + f * 16 + rA) * 32 + kl);
    }
#pragma unroll
    for (int mf = 0; mf < 4; ++mf)
#pragma unroll
      for (int nf = 0; nf < 4; ++nf)
        acc[mf][nf] = __builtin_amdgcn_mfma_f32_16x16x32_bf16(
            a[mf], b[nf], acc[mf][nf], 0, 0, 0);
    __syncthreads();
  }

  const int rgrp = (lane >> 4) * 4;
#pragma unroll
  for (int nf = 0; nf < 4; ++nf) {
    const int col = n0 + wn * 64 + nf * 16 + rA;
    const float bv = bi[col];
#pragma unroll
    for (int mf = 0; mf < 4; ++mf) {
#pragma unroll
      for (int j = 0; j < 4; ++j) {
        const int row = m0 + wm * 64 + mf * 16 + rgrp + j;
        Gi[(size_t)row * 3072 + col] = __float2bfloat16(acc[mf][nf][j] + bv);
      }
    }
  }
}

// ---------------------------------------------------------------------------
// Persistent recurrence. h history IS `out` (f32, unique address per step):
// producers write h via agent stores BEFORE the flag; consumers read h_{t-1}
// with REGULAR cacheable loads (first-touch lines -> fresh from MALL; 4
// same-chain consumers per XCD share the L2 copy). No h16 buffers, no WAR
// (addresses never reused). Flags protocol identical to R6/R10.
// ---------------------------------------------------------------------------
__global__ __launch_bounds__(256, 1) void gru_persist_o(
    const bf16* __restrict__ Whb, const float* __restrict__ bh_f,
    const float* __restrict__ bh_r, const bf16* __restrict__ Gi,
    const float* __restrict__ mask, const float* __restrict__ zbuf,
    unsigned* __restrict__ flags, float* out) {
  __shared__ bf16 hs[32 * 1024];
  const int tid = threadIdx.x;
  const int lane = tid & 63;
  const int w = tid >> 6;
  const int mg = w >> 1;
  const int cg = w & 1;
  const int ct = blockIdx.x;
  const int bt = blockIdx.y;
  const int dir = blockIdx.z;
  unsigned* gflags = flags + (dir * 4 + bt) * 128;

  const float* bh = dir ? bh_r : bh_f;
  const bf16* gi = Gi + (size_t)dir * (32768ull * 3072ull);
  const int bt0 = bt * 32;
  const int rA = lane & 15;
  const int klane = lane >> 4;
  const int row = mg * 16 + rA;
  const int colg = ct * 32 + cg * 16 + rA;

  // r,z B-fragments register-resident; n gate streamed from warm L2.
  const bf16* bp = Whb + (size_t)dir * 3145728 +
                   (size_t)((ct * 2 + cg) * 3) * 16384 + lane * 8;
  bf16x8 br[32], bz[32];
#pragma unroll
  for (int kk = 0; kk < 32; ++kk) br[kk] = *(const bf16x8*)(bp + kk * 512);
#pragma unroll
  for (int kk = 0; kk < 32; ++kk)
    bz[kk] = *(const bf16x8*)(bp + 16384 + kk * 512);
  const bf16* bpn = bp + 32768;

  const float bhr = bh[colg];
  const float bhz = bh[1024 + colg];
  const float bhn = bh[2048 + colg];

  float hp[4] = {0.f, 0.f, 0.f, 0.f};
  const int brow0 = bt0 + mg * 16 + klane * 4;

  float gir[4], giz[4], gin[4], mk4[4];
  {
    const int time0 = dir ? 255 : 0;
#pragma unroll
    for (int j = 0; j < 4; ++j) {
      const size_t gbase = ((size_t)(brow0 + j) * 256 + time0) * 3072 + colg;
      gir[j] = bf2f(gi[gbase]);
      giz[j] = bf2f(gi[gbase + 1024]);
      gin[j] = bf2f(gi[gbase + 2048]);
      mk4[j] = mask[(brow0 + j) * 256 + time0];
    }
  }

  for (int t = 0; t < 256; ++t) {
    const int time = dir ? (255 - t) : t;

    // ---- wait for producers of h_{t-1} (flags >= t) ----
    if (t > 0) {
      if (w == 0) {
        unsigned v;
        do {
          __builtin_amdgcn_s_sleep(1);
          v = ald32(&gflags[lane & 31]);
        } while (__any((int)(v < (unsigned)t)));
      }
      __builtin_amdgcn_sched_barrier(0);
      __syncthreads();
      asm volatile("" ::: "memory");
    }

    // ---- stage h_{t-1}: regular f32 loads -> bf16 -> swizzled LDS ----
    const int tm = dir ? (256 - t) : (t - 1);  // out time index of h_{t-1}
    const float* hsrc0 =
        (t == 0) ? zbuf
                 : out + (size_t)tm * 2048 + dir * 1024 + (size_t)bt0 * 524288;
    const size_t rstride = (t == 0) ? 1024 : 524288;  // f32 per row step
#pragma unroll
    for (int half = 0; half < 2; ++half) {
      float4 va[8], vb[8];
#pragma unroll
      for (int q = 0; q < 8; ++q) {
        const int idx = (half * 8 + q) * 256 + tid;
        const int r = idx >> 7;      // local row 0..31
        const int ch = idx & 127;    // 8-elem chunk
        const float* p = hsrc0 + (size_t)r * rstride + ch * 8;
        va[q] = *(const float4*)p;
        vb[q] = *(const float4*)(p + 4);
      }
#pragma unroll
      for (int q = 0; q < 8; ++q) {
        const int idx = (half * 8 + q) * 256 + tid;
        const int r = idx >> 7;
        const int ch = idx & 127;
        bf16x8 wv;
        wv[0] = f2bf(va[q].x); wv[1] = f2bf(va[q].y);
        wv[2] = f2bf(va[q].z); wv[3] = f2bf(va[q].w);
        wv[4] = f2bf(vb[q].x); wv[5] = f2bf(vb[q].y);
        wv[6] = f2bf(vb[q].z); wv[7] = f2bf(vb[q].w);
        *(bf16x8*)((char*)hs + r * 2048 + ((ch ^ (r & 7)) << 4)) = wv;
      }
    }
    __syncthreads();

    // ---- gh = h @ Wh^T (r,z resident; n streamed) ----
    f32x4 acc0 = {}, acc1 = {}, acc2 = {};
#pragma unroll
    for (int kk = 0; kk < 32; ++kk) {
      const int cidx = kk * 4 + klane;
      bf16x8 a = *(const bf16x8*)(hs + row * 1024 + ((cidx ^ (row & 7)) << 3));
      bf16x8 bn = *(const bf16x8*)(bpn + kk * 512);
      acc0 = __builtin_amdgcn_mfma_f32_16x16x32_bf16(a, br[kk], acc0, 0, 0, 0);
      acc1 = __builtin_amdgcn_mfma_f32_16x16x32_bf16(a, bz[kk], acc1, 0, 0, 0);
      acc2 = __builtin_amdgcn_mfma_f32_16x16x32_bf16(a, bn, acc2, 0, 0, 0);
    }

    // ---- gates; h written to out via AGENT stores (the h transport) ----
#pragma unroll
    for (int j = 0; j < 4; ++j) {
      const float gr = acc0[j] + bhr + gir[j];
      const float gz = acc1[j] + bhz + giz[j];
      const float ghn = acc2[j] + bhn;
      const float r = 1.f / (1.f + __expf(-gr));
      const float z = 1.f / (1.f + __expf(-gz));
      const float nin = gin[j] + r * ghn;
      const float n = 1.f - 2.f / (__expf(2.f * nin) + 1.f);  // tanh
      float hn = (1.f - z) * n + z * hp[j];
      hn = mk4[j] * hn + (1.f - mk4[j]) * hp[j];
      hp[j] = hn;
      ast32(out + ((size_t)(brow0 + j) * 256 + time) * 2048 +
                (size_t)(dir * 1024) + colg,
            __float_as_uint(hn));
    }

    // ---- drain h stores, signal own slot ----
    asm volatile("s_waitcnt vmcnt(0)" ::: "memory");
    __syncthreads();
    if (tid == 0) ast32(&gflags[ct], (unsigned)(t + 1));

    // ---- off-critical-path: next-step gi/mask prefetch ----
    if (t < 255) {
      const int tn = dir ? (254 - t) : (t + 1);
#pragma unroll
      for (int j = 0; j < 4; ++j) {
        const size_t gbase = ((size_t)(brow0 + j) * 256 + tn) * 3072 + colg;
        gir[j] = bf2f(gi[gbase]);
        giz[j] = bf2f(gi[gbase + 1024]);
        gin[j] = bf2f(gi[gbase + 2048]);
        mk4[j] = mask[(brow0 + j) * 256 + tn];
      }
    }
  }
}

// ---------------------------------------------------------------------------
extern "C" void kernel_launch(void* const* d_in, const int* in_sizes, int n_in,
                              void* d_out, int out_size, void* d_ws,
                              size_t ws_size, hipStream_t stream) {
  const float* x = (const float*)d_in[0];
  const float* mask = (const float*)d_in[1];
  const float* Wi_f = (const float*)d_in[2];
  const float* Wh_f = (const float*)d_in[3];
  const float* bi_f = (const float*)d_in[4];
  const float* bh_f = (const float*)d_in[5];
  const float* Wi_r = (const float*)d_in[6];
  const float* Wh_r = (const float*)d_in[7];
  const float* bi_r = (const float*)d_in[8];
  const float* bh_r = (const float*)d_in[9];
  float* out = (float*)d_out;

  char* ws = (char*)d_ws;
  const size_t GI_ELEMS = 32768ull * 3072ull;  // per dir
  bf16* Gi = (bf16*)ws;                                   // 806.4 MB (2 dirs)
  // W region (12.6 MB): Wib_f/Wib_r during GEMMs, then rebuilt as Whb.
  bf16* Wreg = (bf16*)(ws + 2 * GI_ELEMS * sizeof(bf16));
  float* zbuf = (float*)((char*)Wreg + 2 * 3145728 * sizeof(bf16));  // 128 KB
  unsigned* flags = (unsigned*)((char*)zbuf + 131072);               // 4 KB

  hipMemsetAsync(zbuf, 0, 131072 + 4096, stream);

  bf16* Wib_f = Wreg;
  bf16* Wib_r = Wreg + 3145728;
  cvt_bf16<<<1536, 256, 0, stream>>>(Wi_f, Wib_f, 3145728);
  cvt_bf16<<<1536, 256, 0, stream>>>(Wi_r, Wib_r, 3145728);

  gi_gemm<<<dim3(24, 256), 256, 0, stream>>>(x, Wib_f, bi_f, Gi);
  gi_gemm<<<dim3(24, 256), 256, 0, stream>>>(x, Wib_r, bi_r, Gi + GI_ELEMS);

  // Rebuild W region as fragment-ordered Whb (stream-serialized after GEMMs)
  cvt_whb<<<3072, 256, 0, stream>>>(Wh_f, Wh_r, Wreg);

  gru_persist_o<<<dim3(32, 4, 2), 256, 0, stream>>>(Wreg, bh_f, bh_r, Gi,
                                                    mask, zbuf, flags, out);
}

// Round 13
// 4098.022 us; speedup vs baseline: 1.1218x; 1.1218x over previous
//
#include <hip/hip_runtime.h>
#include <hip/hip_bf16.h>

typedef __hip_bfloat16 bf16;
typedef __attribute__((ext_vector_type(8))) short bf16x8;
typedef __attribute__((ext_vector_type(4))) float f32x4;
typedef __attribute__((ext_vector_type(2))) unsigned long long u64x2;

#define GLDS16(g, l)                                                  \
  __builtin_amdgcn_global_load_lds(                                   \
      (const __attribute__((address_space(1))) void*)(g),             \
      (__attribute__((address_space(3))) void*)(l), 16, 0, 0)

__device__ __forceinline__ float bf2f(bf16 v) { return __bfloat162float(v); }
__device__ __forceinline__ short f2bf(float f) {
  bf16 b = __float2bfloat16(f);
  return *reinterpret_cast<short*>(&b);
}

// Proven agent-scope primitives (R6): the cross-block sync/store mechanism.
__device__ __forceinline__ unsigned long long ald64(const void* p) {
  return __hip_atomic_load((const unsigned long long*)p, __ATOMIC_RELAXED,
                           __HIP_MEMORY_SCOPE_AGENT);
}
__device__ __forceinline__ void ast32(void* p, unsigned v) {
  __hip_atomic_store((unsigned*)p, v, __ATOMIC_RELAXED,
                     __HIP_MEMORY_SCOPE_AGENT);
}
__device__ __forceinline__ unsigned ald32(const void* p) {
  return __hip_atomic_load((const unsigned*)p, __ATOMIC_RELAXED,
                           __HIP_MEMORY_SCOPE_AGENT);
}

// ---------------------------------------------------------------------------
// f32 -> bf16 linear conversion, 8 elems/thread
// ---------------------------------------------------------------------------
__global__ __launch_bounds__(256) void cvt_bf16(const float* __restrict__ in,
                                                bf16* __restrict__ out, int n) {
  const int i = (blockIdx.x * 256 + threadIdx.x) * 8;
  if (i >= n) return;
  const float4 u = *(const float4*)(in + i);
  const float4 v = *(const float4*)(in + i + 4);
  bf16x8 w;
  w[0] = f2bf(u.x); w[1] = f2bf(u.y); w[2] = f2bf(u.z); w[3] = f2bf(u.w);
  w[4] = f2bf(v.x); w[5] = f2bf(v.y); w[6] = f2bf(v.z); w[7] = f2bf(v.w);
  *(bf16x8*)(out + i) = w;
}

// ---------------------------------------------------------------------------
// Wh (f32, [3072][1024] per dir) -> bf16 in MFMA B-fragment order:
// Whb[dir][cg(64)][gate(3)][kk(32)][lane(64)][8]
// ---------------------------------------------------------------------------
__global__ __launch_bounds__(256) void cvt_whb(const float* __restrict__ Wh_f,
                                               const float* __restrict__ Wh_r,
                                               bf16* __restrict__ Whb) {
  const int t = blockIdx.x * 256 + threadIdx.x;  // 786432 threads
  const int d = t / 393216;
  int r = t % 393216;
  const int cg = r / 6144;  r %= 6144;
  const int g = r / 2048;   r %= 2048;
  const int kk = r / 64;
  const int lane = r & 63;
  const float* Wh = d ? Wh_r : Wh_f;
  const int row = g * 1024 + cg * 16 + (lane & 15);
  const int col = kk * 32 + (lane >> 4) * 8;
  const float* s = Wh + (size_t)row * 1024 + col;
  const float4 u = *(const float4*)s;
  const float4 v = *(const float4*)(s + 4);
  bf16x8 w;
  w[0] = f2bf(u.x); w[1] = f2bf(u.y); w[2] = f2bf(u.z); w[3] = f2bf(u.w);
  w[4] = f2bf(v.x); w[5] = f2bf(v.y); w[6] = f2bf(v.z); w[7] = f2bf(v.w);
  *(bf16x8*)(Whb + (size_t)t * 8) = w;
}

// ---------------------------------------------------------------------------
// Prologue: Gi[32768][3072] = Xb @ Wib^T + bi   (all bf16, m97-style GLDS)
// ---------------------------------------------------------------------------
__global__ __launch_bounds__(256) void gi_gemm(const bf16* __restrict__ X,
                                               const bf16* __restrict__ Wi,
                                               const float* __restrict__ bi,
                                               bf16* __restrict__ Gi) {
  __shared__ bf16 As[128 * 32];
  __shared__ bf16 Bs[128 * 32];
  const int tid = threadIdx.x;
  const int lane = tid & 63;
  const int w = tid >> 6;
  const int wm = w >> 1, wn = w & 1;
  const int m0 = blockIdx.y * 128;
  const int n0 = blockIdx.x * 128;
  const int rA = lane & 15;
  const int kl = (lane >> 4) * 8;

  f32x4 acc[4][4] = {};

  const bf16* Ab = X + (size_t)m0 * 1024;
  const bf16* Bb = Wi + (size_t)n0 * 1024;

  const int arow = tid >> 2;
  const int akk = (tid & 3) * 8;

  for (int kt = 0; kt < 1024; kt += 32) {
#pragma unroll
    for (int i = 0; i < 2; ++i) {
      GLDS16(Ab + (size_t)(i * 64 + arow) * 1024 + kt + akk,
             As + (i * 256 + w * 64) * 8);
      GLDS16(Bb + (size_t)(i * 64 + arow) * 1024 + kt + akk,
             Bs + (i * 256 + w * 64) * 8);
    }
    asm volatile("s_waitcnt vmcnt(0)" ::: "memory");
    __syncthreads();

    bf16x8 a[4], b[4];
#pragma unroll
    for (int f = 0; f < 4; ++f) {
      a[f] = *(const bf16x8*)(As + (wm * 64 + f * 16 + rA) * 32 + kl);
      b[f] = *(const bf16x8*)(Bs + (wn * 64 + f * 16 + rA) * 32 + kl);
    }
#pragma unroll
    for (int mf = 0; mf < 4; ++mf)
#pragma unroll
      for (int nf = 0; nf < 4; ++nf)
        acc[mf][nf] = __builtin_amdgcn_mfma_f32_16x16x32_bf16(
            a[mf], b[nf], acc[mf][nf], 0, 0, 0);
    __syncthreads();
  }

  const int rgrp = (lane >> 4) * 4;
#pragma unroll
  for (int nf = 0; nf < 4; ++nf) {
    const int col = n0 + wn * 64 + nf * 16 + rA;
    const float bv = bi[col];
#pragma unroll
    for (int mf = 0; mf < 4; ++mf) {
#pragma unroll
      for (int j = 0; j < 4; ++j) {
        const int row = m0 + wm * 64 + mf * 16 + rgrp + j;
        Gi[(size_t)row * 3072 + col] = __float2bfloat16(acc[mf][nf][j] + bv);
      }
    }
  }
}

// ===========================================================================
// RING-PATH recurrence: h history in a unique-address bf16 ring
// ring[t][dir][row128][col1024] (512KB/slot). Producers: agent stores +
// drain + flag (R6 protocol). Consumers: poll flags, then REGULAR cacheable
// 16B loads of a contiguous 64KB slab (first touch -> MALL; same-XCD
// consumers share the L2 copy). Everything else identical to R10.
// ===========================================================================
__global__ __launch_bounds__(256, 1) void gru_persist_r(
    const bf16* __restrict__ Whb, const float* __restrict__ bh_f,
    const float* __restrict__ bh_r, const bf16* __restrict__ Gi,
    const float* __restrict__ mask, const bf16* __restrict__ zbuf,
    bf16* __restrict__ ring, unsigned* __restrict__ flags,
    float* __restrict__ out) {
  __shared__ bf16 hs[32 * 1024];
  const int tid = threadIdx.x;
  const int lane = tid & 63;
  const int w = tid >> 6;
  const int mg = w >> 1;
  const int cg = w & 1;
  const int ct = blockIdx.x;
  const int bt = blockIdx.y;
  const int dir = blockIdx.z;
  unsigned* gflags = flags + (dir * 4 + bt) * 128;

  const float* bh = dir ? bh_r : bh_f;
  const bf16* gi = Gi + (size_t)dir * (32768ull * 3072ull);
  const int bt0 = bt * 32;
  const int rA = lane & 15;
  const int klane = lane >> 4;
  const int row = mg * 16 + rA;
  const int colg = ct * 32 + cg * 16 + rA;

  const bf16* bp = Whb + (size_t)dir * 3145728 +
                   (size_t)((ct * 2 + cg) * 3) * 16384 + lane * 8;
  bf16x8 br[32], bz[32];
#pragma unroll
  for (int kk = 0; kk < 32; ++kk) br[kk] = *(const bf16x8*)(bp + kk * 512);
#pragma unroll
  for (int kk = 0; kk < 32; ++kk)
    bz[kk] = *(const bf16x8*)(bp + 16384 + kk * 512);
  const bf16* bpn = bp + 32768;

  const float bhr = bh[colg];
  const float bhz = bh[1024 + colg];
  const float bhn = bh[2048 + colg];

  float hp[4] = {0.f, 0.f, 0.f, 0.f};
  const int brow0 = bt0 + mg * 16 + klane * 4;

  float gir[4], giz[4], gin[4], mk4[4];
  {
    const int time0 = dir ? 255 : 0;
#pragma unroll
    for (int j = 0; j < 4; ++j) {
      const size_t gbase = ((size_t)(brow0 + j) * 256 + time0) * 3072 + colg;
      gir[j] = bf2f(gi[gbase]);
      giz[j] = bf2f(gi[gbase + 1024]);
      gin[j] = bf2f(gi[gbase + 2048]);
      mk4[j] = mask[(brow0 + j) * 256 + time0];
    }
  }

  for (int t = 0; t < 256; ++t) {
    const int time = dir ? (255 - t) : t;

    // ---- wait for producers of h_{t-1} (flags >= t) ----
    if (t > 0) {
      if (w == 0) {
        unsigned v;
        do {
          __builtin_amdgcn_s_sleep(1);
          v = ald32(&gflags[lane & 31]);
        } while (__any((int)(v < (unsigned)t)));
      }
      __builtin_amdgcn_sched_barrier(0);
      __syncthreads();
      asm volatile("" ::: "memory");
    }

    // ---- stage h_{t-1}: regular cacheable 16B loads of 64KB slab ----
    const bf16* hsrc =
        (t == 0) ? (zbuf + (size_t)bt0 * 1024)
                 : (ring + (size_t)(t - 1) * 262144 + (size_t)dir * 131072 +
                    (size_t)bt0 * 1024);
    {
      u64x2 v[16];
#pragma unroll
      for (int q = 0; q < 16; ++q) {
        const int idx = q * 256 + tid;
        const int r = idx >> 7;      // local row 0..31
        const int ch = idx & 127;    // 16B chunk within row
        v[q] = *(const u64x2*)(hsrc + ((size_t)r << 10) + ch * 8);
      }
#pragma unroll
      for (int q = 0; q < 16; ++q) {
        const int idx = q * 256 + tid;
        const int r = idx >> 7;
        const int ch = idx & 127;
        *(u64x2*)((char*)hs + r * 2048 + ((ch ^ (r & 7)) << 4)) = v[q];
      }
    }
    __syncthreads();

    // ---- gh = h @ Wh^T (r,z resident; n streamed) ----
    f32x4 acc0 = {}, acc1 = {}, acc2 = {};
#pragma unroll
    for (int kk = 0; kk < 32; ++kk) {
      const int cidx = kk * 4 + klane;
      bf16x8 a = *(const bf16x8*)(hs + row * 1024 + ((cidx ^ (row & 7)) << 3));
      bf16x8 bn = *(const bf16x8*)(bpn + kk * 512);
      acc0 = __builtin_amdgcn_mfma_f32_16x16x32_bf16(a, br[kk], acc0, 0, 0, 0);
      acc1 = __builtin_amdgcn_mfma_f32_16x16x32_bf16(a, bz[kk], acc1, 0, 0, 0);
      acc2 = __builtin_amdgcn_mfma_f32_16x16x32_bf16(a, bn, acc2, 0, 0, 0);
    }

    // ---- gates; packed dword h stores into ring slot t (agent) ----
    bf16* hdst = ring + (size_t)t * 262144 + (size_t)dir * 131072;
    float hnv[4];
#pragma unroll
    for (int j = 0; j < 4; ++j) {
      const float gr = acc0[j] + bhr + gir[j];
      const float gz = acc1[j] + bhz + giz[j];
      const float ghn = acc2[j] + bhn;
      const float r = 1.f / (1.f + __expf(-gr));
      const float z = 1.f / (1.f + __expf(-gz));
      const float nin = gin[j] + r * ghn;
      const float n = 1.f - 2.f / (__expf(2.f * nin) + 1.f);  // tanh
      float hn = (1.f - z) * n + z * hp[j];
      hn = mk4[j] * hn + (1.f - mk4[j]) * hp[j];
      hp[j] = hn;
      hnv[j] = hn;
      const unsigned short hb = (unsigned short)f2bf(hn);
      const unsigned nb = (unsigned)__shfl_xor((int)hb, 1);
      if (!(lane & 1))
        ast32(hdst + (((size_t)brow0 + j) << 10) + colg,
              (unsigned)hb | (nb << 16));
    }

    // ---- drain h stores, signal own slot ----
    asm volatile("s_waitcnt vmcnt(0)" ::: "memory");
    __syncthreads();
    if (tid == 0) ast32(&gflags[ct], (unsigned)(t + 1));

    // ---- off-critical-path: out stores + next-step gi/mask prefetch ----
#pragma unroll
    for (int j = 0; j < 4; ++j)
      out[(((size_t)(brow0 + j)) * 256 + time) * 2048 + (size_t)(dir * 1024) +
          colg] = hnv[j];

    if (t < 255) {
      const int tn = dir ? (254 - t) : (t + 1);
#pragma unroll
      for (int j = 0; j < 4; ++j) {
        const size_t gbase = ((size_t)(brow0 + j) * 256 + tn) * 3072 + colg;
        gir[j] = bf2f(gi[gbase]);
        giz[j] = bf2f(gi[gbase + 1024]);
        gin[j] = bf2f(gi[gbase + 2048]);
        mk4[j] = mask[(brow0 + j) * 256 + tn];
      }
    }
  }
}

// ===========================================================================
// FALLBACK recurrence: R10 kernel verbatim (proven 2.48 ms).
// ===========================================================================
__global__ __launch_bounds__(256, 1) void gru_persist_s(
    const bf16* __restrict__ Whb, const float* __restrict__ bh_f,
    const float* __restrict__ bh_r, const bf16* __restrict__ Gi,
    const float* __restrict__ mask, bf16* __restrict__ h16,
    unsigned* __restrict__ flags, float* __restrict__ out) {
  __shared__ bf16 hs[32 * 1024];
  const int tid = threadIdx.x;
  const int lane = tid & 63;
  const int w = tid >> 6;
  const int mg = w >> 1;
  const int cg = w & 1;
  const int ct = blockIdx.x;
  const int bt = blockIdx.y;
  const int dir = blockIdx.z;
  unsigned* gflags = flags + (dir * 4 + bt) * 128;

  const float* bh = dir ? bh_r : bh_f;
  const bf16* gi = Gi + (size_t)dir * (32768ull * 3072ull);
  const int bt0 = bt * 32;
  const int rA = lane & 15;
  const int klane = lane >> 4;
  const int row = mg * 16 + rA;
  const int colg = ct * 32 + cg * 16 + rA;

  bf16* hbuf0 = h16 + (size_t)(dir * 2 + 0) * 131072;
  bf16* hbuf1 = h16 + (size_t)(dir * 2 + 1) * 131072;

  const bf16* bp = Whb + (size_t)dir * 3145728 +
                   (size_t)((ct * 2 + cg) * 3) * 16384 + lane * 8;
  bf16x8 br[32], bz[32];
#pragma unroll
  for (int kk = 0; kk < 32; ++kk) br[kk] = *(const bf16x8*)(bp + kk * 512);
#pragma unroll
  for (int kk = 0; kk < 32; ++kk)
    bz[kk] = *(const bf16x8*)(bp + 16384 + kk * 512);
  const bf16* bpn = bp + 32768;

  const float bhr = bh[colg];
  const float bhz = bh[1024 + colg];
  const float bhn = bh[2048 + colg];

  float hp[4] = {0.f, 0.f, 0.f, 0.f};
  const int brow0 = bt0 + mg * 16 + klane * 4;

  float gir[4], giz[4], gin[4], mk4[4];
  {
    const int time0 = dir ? 255 : 0;
#pragma unroll
    for (int j = 0; j < 4; ++j) {
      const size_t gbase = ((size_t)(brow0 + j) * 256 + time0) * 3072 + colg;
      gir[j] = bf2f(gi[gbase]);
      giz[j] = bf2f(gi[gbase + 1024]);
      gin[j] = bf2f(gi[gbase + 2048]);
      mk4[j] = mask[(brow0 + j) * 256 + time0];
    }
  }

  for (int t = 0; t < 256; ++t) {
    const int time = dir ? (255 - t) : t;
    bf16* hin = (t & 1) ? hbuf1 : hbuf0;
    bf16* hout = (t & 1) ? hbuf0 : hbuf1;

#pragma unroll
    for (int half = 0; half < 2; ++half) {
      unsigned long long vv[16];
#pragma unroll
      for (int q = 0; q < 16; ++q) {
        const int idx = (half * 16 + q) * 256 + tid;
        const int r = idx >> 8;
        const int c8 = idx & 255;
        vv[q] = ald64(hin + ((size_t)(bt0 + r) << 10) + c8 * 4);
      }
#pragma unroll
      for (int q = 0; q < 16; ++q) {
        const int idx = (half * 16 + q) * 256 + tid;
        const int r = idx >> 8;
        const int c8 = idx & 255;
        const int sw = (((c8 >> 1) ^ (r & 7)) << 4) | ((c8 & 1) << 3);
        *(unsigned long long*)((char*)hs + r * 2048 + sw) = vv[q];
      }
    }
    __syncthreads();

    f32x4 acc0 = {}, acc1 = {}, acc2 = {};
#pragma unroll
    for (int kk = 0; kk < 32; ++kk) {
      const int cidx = kk * 4 + klane;
      bf16x8 a = *(const bf16x8*)(hs + row * 1024 + ((cidx ^ (row & 7)) << 3));
      bf16x8 bn = *(const bf16x8*)(bpn + kk * 512);
      acc0 = __builtin_amdgcn_mfma_f32_16x16x32_bf16(a, br[kk], acc0, 0, 0, 0);
      acc1 = __builtin_amdgcn_mfma_f32_16x16x32_bf16(a, bz[kk], acc1, 0, 0, 0);
      acc2 = __builtin_amdgcn_mfma_f32_16x16x32_bf16(a, bn, acc2, 0, 0, 0);
    }

    float hnv[4];
#pragma unroll
    for (int j = 0; j < 4; ++j) {
      const float gr = acc0[j] + bhr + gir[j];
      const float gz = acc1[j] + bhz + giz[j];
      const float ghn = acc2[j] + bhn;
      const float r = 1.f / (1.f + __expf(-gr));
      const float z = 1.f / (1.f + __expf(-gz));
      const float nin = gin[j] + r * ghn;
      const float n = 1.f - 2.f / (__expf(2.f * nin) + 1.f);
      float hn = (1.f - z) * n + z * hp[j];
      hn = mk4[j] * hn + (1.f - mk4[j]) * hp[j];
      hp[j] = hn;
      hnv[j] = hn;
      const unsigned short hb = (unsigned short)f2bf(hn);
      const unsigned nb = (unsigned)__shfl_xor((int)hb, 1);
      if (!(lane & 1))
        ast32(hout + (((size_t)brow0 + j) << 10) + colg,
              (unsigned)hb | (nb << 16));
    }

    asm volatile("s_waitcnt vmcnt(0)" ::: "memory");
    __syncthreads();
    if (tid == 0) ast32(&gflags[ct], (unsigned)(t + 1));

#pragma unroll
    for (int j = 0; j < 4; ++j)
      out[(((size_t)(brow0 + j)) * 256 + time) * 2048 + (size_t)(dir * 1024) +
          colg] = hnv[j];

    if (t < 255) {
      const int tn = dir ? (254 - t) : (t + 1);
#pragma unroll
      for (int j = 0; j < 4; ++j) {
        const size_t gbase = ((size_t)(brow0 + j) * 256 + tn) * 3072 + colg;
        gir[j] = bf2f(gi[gbase]);
        giz[j] = bf2f(gi[gbase + 1024]);
        gin[j] = bf2f(gi[gbase + 2048]);
        mk4[j] = mask[(brow0 + j) * 256 + tn];
      }
      if (w == 0) {
        unsigned v;
        do {
          __builtin_amdgcn_s_sleep(1);
          v = ald32(&gflags[lane & 31]);
        } while (__any((int)(v < (unsigned)(t + 1))));
      }
      __builtin_amdgcn_sched_barrier(0);
      __syncthreads();
    }
  }
}

// ---------------------------------------------------------------------------
extern "C" void kernel_launch(void* const* d_in, const int* in_sizes, int n_in,
                              void* d_out, int out_size, void* d_ws,
                              size_t ws_size, hipStream_t stream) {
  const float* x = (const float*)d_in[0];
  const float* mask = (const float*)d_in[1];
  const float* Wi_f = (const float*)d_in[2];
  const float* Wh_f = (const float*)d_in[3];
  const float* bi_f = (const float*)d_in[4];
  const float* bh_f = (const float*)d_in[5];
  const float* Wi_r = (const float*)d_in[6];
  const float* Wh_r = (const float*)d_in[7];
  const float* bi_r = (const float*)d_in[8];
  const float* bh_r = (const float*)d_in[9];
  float* out = (float*)d_out;

  char* ws = (char*)d_ws;
  const size_t GI_ELEMS = 32768ull * 3072ull;  // per dir
  bf16* Gi = (bf16*)ws;                                   // 402.7 MB total
  bf16* Whb = (bf16*)(ws + 2 * GI_ELEMS * sizeof(bf16));  // 12.6 MB
  bf16* h16 = Whb + 2 * 3145728;                          // 1 MB (fallback)
  unsigned* flags = (unsigned*)((char*)h16 + 1048576);    // 4 KB
  bf16* zbuf = (bf16*)((char*)flags + 4096);              // 256 KB zeros
  bf16* ring = (bf16*)((char*)zbuf + 262144);             // 134.2 MB
  const size_t ring_end =
      (size_t)((char*)ring - ws) + 256ull * 262144ull * sizeof(bf16);
  const bool use_ring = ws_size >= ring_end;

  // bf16 X / Wi scratch lives in d_out (fully overwritten afterwards)
  bf16* Xb = (bf16*)d_out;
  bf16* Wib_f = Xb + 33554432;
  bf16* Wib_r = Wib_f + 3145728;

  // zero h16 + flags + zbuf (contiguous)
  hipMemsetAsync(h16, 0, 1048576 + 4096 + 262144, stream);

  cvt_bf16<<<16384, 256, 0, stream>>>(x, Xb, 33554432);
  cvt_bf16<<<1536, 256, 0, stream>>>(Wi_f, Wib_f, 3145728);
  cvt_bf16<<<1536, 256, 0, stream>>>(Wi_r, Wib_r, 3145728);
  cvt_whb<<<3072, 256, 0, stream>>>(Wh_f, Wh_r, Whb);

  gi_gemm<<<dim3(24, 256), 256, 0, stream>>>(Xb, Wib_f, bi_f, Gi);
  gi_gemm<<<dim3(24, 256), 256, 0, stream>>>(Xb, Wib_r, bi_r, Gi + GI_ELEMS);

  if (use_ring)
    gru_persist_r<<<dim3(32, 4, 2), 256, 0, stream>>>(
        Whb, bh_f, bh_r, Gi, mask, zbuf, ring, flags, out);
  else
    gru_persist_s<<<dim3(32, 4, 2), 256, 0, stream>>>(Whb, bh_f, bh_r, Gi,
                                                      mask, h16, flags, out);
}

// Round 14
// 2468.526 us; speedup vs baseline: 1.8624x; 1.6601x over previous
//
#include <hip/hip_runtime.h>
#include <hip/hip_bf16.h>

typedef __hip_bfloat16 bf16;
typedef __attribute__((ext_vector_type(8))) short bf16x8;
typedef __attribute__((ext_vector_type(4))) float f32x4;

#define GLDS16(g, l)                                                  \
  __builtin_amdgcn_global_load_lds(                                   \
      (const __attribute__((address_space(1))) void*)(g),             \
      (__attribute__((address_space(3))) void*)(l), 16, 0, 0)

__device__ __forceinline__ float bf2f(bf16 v) { return __bfloat162float(v); }
__device__ __forceinline__ short f2bf(float f) {
  bf16 b = __float2bfloat16(f);
  return *reinterpret_cast<short*>(&b);
}

// Proven agent-scope primitives (R6): the ONLY cross-block comm mechanism.
__device__ __forceinline__ unsigned long long ald64(const void* p) {
  return __hip_atomic_load((const unsigned long long*)p, __ATOMIC_RELAXED,
                           __HIP_MEMORY_SCOPE_AGENT);
}
__device__ __forceinline__ void ast32(void* p, unsigned v) {
  __hip_atomic_store((unsigned*)p, v, __ATOMIC_RELAXED,
                     __HIP_MEMORY_SCOPE_AGENT);
}
__device__ __forceinline__ unsigned ald32(const void* p) {
  return __hip_atomic_load((const unsigned*)p, __ATOMIC_RELAXED,
                           __HIP_MEMORY_SCOPE_AGENT);
}

// ---------------------------------------------------------------------------
// f32 -> bf16 linear conversion, 8 elems/thread
// ---------------------------------------------------------------------------
__global__ __launch_bounds__(256) void cvt_bf16(const float* __restrict__ in,
                                                bf16* __restrict__ out, int n) {
  const int i = (blockIdx.x * 256 + threadIdx.x) * 8;
  if (i >= n) return;
  const float4 u = *(const float4*)(in + i);
  const float4 v = *(const float4*)(in + i + 4);
  bf16x8 w;
  w[0] = f2bf(u.x); w[1] = f2bf(u.y); w[2] = f2bf(u.z); w[3] = f2bf(u.w);
  w[4] = f2bf(v.x); w[5] = f2bf(v.y); w[6] = f2bf(v.z); w[7] = f2bf(v.w);
  *(bf16x8*)(out + i) = w;
}

// ---------------------------------------------------------------------------
// Wh (f32, [3072][1024] per dir) -> bf16 in MFMA B-fragment order:
// Whb[dir][cg(64)][gate(3)][kk(32)][lane(64)][8]
// ---------------------------------------------------------------------------
__global__ __launch_bounds__(256) void cvt_whb(const float* __restrict__ Wh_f,
                                               const float* __restrict__ Wh_r,
                                               bf16* __restrict__ Whb) {
  const int t = blockIdx.x * 256 + threadIdx.x;  // 786432 threads
  const int d = t / 393216;
  int r = t % 393216;
  const int cg = r / 6144;  r %= 6144;
  const int g = r / 2048;   r %= 2048;
  const int kk = r / 64;
  const int lane = r & 63;
  const float* Wh = d ? Wh_r : Wh_f;
  const int row = g * 1024 + cg * 16 + (lane & 15);
  const int col = kk * 32 + (lane >> 4) * 8;
  const float* s = Wh + (size_t)row * 1024 + col;
  const float4 u = *(const float4*)s;
  const float4 v = *(const float4*)(s + 4);
  bf16x8 w;
  w[0] = f2bf(u.x); w[1] = f2bf(u.y); w[2] = f2bf(u.z); w[3] = f2bf(u.w);
  w[4] = f2bf(v.x); w[5] = f2bf(v.y); w[6] = f2bf(v.z); w[7] = f2bf(v.w);
  *(bf16x8*)(Whb + (size_t)t * 8) = w;
}

// ---------------------------------------------------------------------------
// Prologue: Gi[32768][3072] = Xb @ Wib^T + bi   (all bf16, m97-style GLDS)
// ---------------------------------------------------------------------------
__global__ __launch_bounds__(256) void gi_gemm(const bf16* __restrict__ X,
                                               const bf16* __restrict__ Wi,
                                               const float* __restrict__ bi,
                                               bf16* __restrict__ Gi) {
  __shared__ bf16 As[128 * 32];
  __shared__ bf16 Bs[128 * 32];
  const int tid = threadIdx.x;
  const int lane = tid & 63;
  const int w = tid >> 6;
  const int wm = w >> 1, wn = w & 1;
  const int m0 = blockIdx.y * 128;
  const int n0 = blockIdx.x * 128;
  const int rA = lane & 15;
  const int kl = (lane >> 4) * 8;

  f32x4 acc[4][4] = {};

  const bf16* Ab = X + (size_t)m0 * 1024;
  const bf16* Bb = Wi + (size_t)n0 * 1024;

  const int arow = tid >> 2;
  const int akk = (tid & 3) * 8;

  for (int kt = 0; kt < 1024; kt += 32) {
#pragma unroll
    for (int i = 0; i < 2; ++i) {
      GLDS16(Ab + (size_t)(i * 64 + arow) * 1024 + kt + akk,
             As + (i * 256 + w * 64) * 8);
      GLDS16(Bb + (size_t)(i * 64 + arow) * 1024 + kt + akk,
             Bs + (i * 256 + w * 64) * 8);
    }
    asm volatile("s_waitcnt vmcnt(0)" ::: "memory");
    __syncthreads();

    bf16x8 a[4], b[4];
#pragma unroll
    for (int f = 0; f < 4; ++f) {
      a[f] = *(const bf16x8*)(As + (wm * 64 + f * 16 + rA) * 32 + kl);
      b[f] = *(const bf16x8*)(Bs + (wn * 64 + f * 16 + rA) * 32 + kl);
    }
#pragma unroll
    for (int mf = 0; mf < 4; ++mf)
#pragma unroll
      for (int nf = 0; nf < 4; ++nf)
        acc[mf][nf] = __builtin_amdgcn_mfma_f32_16x16x32_bf16(
            a[mf], b[nf], acc[mf][nf], 0, 0, 0);
    __syncthreads();
  }

  const int rgrp = (lane >> 4) * 4;
#pragma unroll
  for (int nf = 0; nf < 4; ++nf) {
    const int col = n0 + wn * 64 + nf * 16 + rA;
    const float bv = bi[col];
#pragma unroll
    for (int mf = 0; mf < 4; ++mf) {
#pragma unroll
      for (int j = 0; j < 4; ++j) {
        const int row = m0 + wm * 64 + mf * 16 + rgrp + j;
        Gi[(size_t)row * 3072 + col] = __float2bfloat16(acc[mf][nf][j] + bv);
      }
    }
  }
}

// ---------------------------------------------------------------------------
// Persistent recurrence = R10 (best measured) with ALL THREE gate weight
// sets register-resident (~96 VGPRs of fragments; no per-step L2 weight
// stream). Grid (32 ct, 4 bt, 2 dir) = 256 blocks, 256 threads = 4 waves.
// ---------------------------------------------------------------------------
__global__ __launch_bounds__(256, 1) void gru_persist_s(
    const bf16* __restrict__ Whb, const float* __restrict__ bh_f,
    const float* __restrict__ bh_r, const bf16* __restrict__ Gi,
    const float* __restrict__ mask, bf16* __restrict__ h16,
    unsigned* __restrict__ flags, float* __restrict__ out) {
  __shared__ bf16 hs[32 * 1024];
  const int tid = threadIdx.x;
  const int lane = tid & 63;
  const int w = tid >> 6;
  const int mg = w >> 1;
  const int cg = w & 1;
  const int ct = blockIdx.x;
  const int bt = blockIdx.y;
  const int dir = blockIdx.z;
  unsigned* gflags = flags + (dir * 4 + bt) * 128;

  const float* bh = dir ? bh_r : bh_f;
  const bf16* gi = Gi + (size_t)dir * (32768ull * 3072ull);
  const int bt0 = bt * 32;
  const int rA = lane & 15;
  const int klane = lane >> 4;
  const int row = mg * 16 + rA;
  const int colg = ct * 32 + cg * 16 + rA;

  bf16* hbuf0 = h16 + (size_t)(dir * 2 + 0) * 131072;
  bf16* hbuf1 = h16 + (size_t)(dir * 2 + 1) * 131072;

  // ALL gate B-fragments register-resident (r, z, n): 96 VGPRs.
  const bf16* bp = Whb + (size_t)dir * 3145728 +
                   (size_t)((ct * 2 + cg) * 3) * 16384 + lane * 8;
  bf16x8 br[32], bz[32], bn[32];
#pragma unroll
  for (int kk = 0; kk < 32; ++kk) br[kk] = *(const bf16x8*)(bp + kk * 512);
#pragma unroll
  for (int kk = 0; kk < 32; ++kk)
    bz[kk] = *(const bf16x8*)(bp + 16384 + kk * 512);
#pragma unroll
  for (int kk = 0; kk < 32; ++kk)
    bn[kk] = *(const bf16x8*)(bp + 32768 + kk * 512);

  const float bhr = bh[colg];
  const float bhz = bh[1024 + colg];
  const float bhn = bh[2048 + colg];

  float hp[4] = {0.f, 0.f, 0.f, 0.f};
  const int brow0 = bt0 + mg * 16 + klane * 4;

  float gir[4], giz[4], gin[4], mk4[4];
  {
    const int time0 = dir ? 255 : 0;
#pragma unroll
    for (int j = 0; j < 4; ++j) {
      const size_t gbase = ((size_t)(brow0 + j) * 256 + time0) * 3072 + colg;
      gir[j] = bf2f(gi[gbase]);
      giz[j] = bf2f(gi[gbase + 1024]);
      gin[j] = bf2f(gi[gbase + 2048]);
      mk4[j] = mask[(brow0 + j) * 256 + time0];
    }
  }

  for (int t = 0; t < 256; ++t) {
    const int time = dir ? (255 - t) : t;
    bf16* hin = (t & 1) ? hbuf1 : hbuf0;
    bf16* hout = (t & 1) ? hbuf0 : hbuf1;

    // ---- stage h tile: agent 8B loads -> swizzled LDS (R6-proven) ----
#pragma unroll
    for (int half = 0; half < 2; ++half) {
      unsigned long long vv[16];
#pragma unroll
      for (int q = 0; q < 16; ++q) {
        const int idx = (half * 16 + q) * 256 + tid;
        const int r = idx >> 8;
        const int c8 = idx & 255;
        vv[q] = ald64(hin + ((size_t)(bt0 + r) << 10) + c8 * 4);
      }
#pragma unroll
      for (int q = 0; q < 16; ++q) {
        const int idx = (half * 16 + q) * 256 + tid;
        const int r = idx >> 8;
        const int c8 = idx & 255;
        const int sw = (((c8 >> 1) ^ (r & 7)) << 4) | ((c8 & 1) << 3);
        *(unsigned long long*)((char*)hs + r * 2048 + sw) = vv[q];
      }
    }
    __syncthreads();

    // ---- gh = h @ Wh^T: pure {LDS read + MFMA}, all weights in regs ----
    f32x4 acc0 = {}, acc1 = {}, acc2 = {};
#pragma unroll
    for (int kk = 0; kk < 32; ++kk) {
      const int cidx = kk * 4 + klane;
      bf16x8 a = *(const bf16x8*)(hs + row * 1024 + ((cidx ^ (row & 7)) << 3));
      acc0 = __builtin_amdgcn_mfma_f32_16x16x32_bf16(a, br[kk], acc0, 0, 0, 0);
      acc1 = __builtin_amdgcn_mfma_f32_16x16x32_bf16(a, bz[kk], acc1, 0, 0, 0);
      acc2 = __builtin_amdgcn_mfma_f32_16x16x32_bf16(a, bn[kk], acc2, 0, 0, 0);
    }

    // ---- gates; ONLY packed h stores before the drain ----
    float hnv[4];
#pragma unroll
    for (int j = 0; j < 4; ++j) {
      const float gr = acc0[j] + bhr + gir[j];
      const float gz = acc1[j] + bhz + giz[j];
      const float ghn = acc2[j] + bhn;
      const float r = 1.f / (1.f + __expf(-gr));
      const float z = 1.f / (1.f + __expf(-gz));
      const float nin = gin[j] + r * ghn;
      const float n = 1.f - 2.f / (__expf(2.f * nin) + 1.f);  // tanh
      float hn = (1.f - z) * n + z * hp[j];
      hn = mk4[j] * hn + (1.f - mk4[j]) * hp[j];
      hp[j] = hn;
      hnv[j] = hn;
      const unsigned short hb = (unsigned short)f2bf(hn);
      const unsigned nb = (unsigned)__shfl_xor((int)hb, 1);
      if (!(lane & 1))
        ast32(hout + (((size_t)brow0 + j) << 10) + colg,
              (unsigned)hb | (nb << 16));
    }

    // ---- drain h stores only, signal own slot ----
    asm volatile("s_waitcnt vmcnt(0)" ::: "memory");
    __syncthreads();
    if (tid == 0) ast32(&gflags[ct], (unsigned)(t + 1));

    // ---- off-critical-path: out stores + next-step gi/mask prefetch ----
#pragma unroll
    for (int j = 0; j < 4; ++j)
      out[(((size_t)(brow0 + j)) * 256 + time) * 2048 + (size_t)(dir * 1024) +
          colg] = hnv[j];

    if (t < 255) {
      const int tn = dir ? (254 - t) : (t + 1);
#pragma unroll
      for (int j = 0; j < 4; ++j) {
        const size_t gbase = ((size_t)(brow0 + j) * 256 + tn) * 3072 + colg;
        gir[j] = bf2f(gi[gbase]);
        giz[j] = bf2f(gi[gbase + 1024]);
        gin[j] = bf2f(gi[gbase + 2048]);
        mk4[j] = mask[(brow0 + j) * 256 + tn];
      }
      if (w == 0) {
        unsigned v;
        do {
          __builtin_amdgcn_s_sleep(1);
          v = ald32(&gflags[lane & 31]);
        } while (__any((int)(v < (unsigned)(t + 1))));
      }
      __builtin_amdgcn_sched_barrier(0);
      __syncthreads();
    }
  }
}

// ---------------------------------------------------------------------------
extern "C" void kernel_launch(void* const* d_in, const int* in_sizes, int n_in,
                              void* d_out, int out_size, void* d_ws,
                              size_t ws_size, hipStream_t stream) {
  const float* x = (const float*)d_in[0];
  const float* mask = (const float*)d_in[1];
  const float* Wi_f = (const float*)d_in[2];
  const float* Wh_f = (const float*)d_in[3];
  const float* bi_f = (const float*)d_in[4];
  const float* bh_f = (const float*)d_in[5];
  const float* Wi_r = (const float*)d_in[6];
  const float* Wh_r = (const float*)d_in[7];
  const float* bi_r = (const float*)d_in[8];
  const float* bh_r = (const float*)d_in[9];
  float* out = (float*)d_out;

  char* ws = (char*)d_ws;
  const size_t GI_ELEMS = 32768ull * 3072ull;  // per dir
  bf16* Gi = (bf16*)ws;                                   // 402.7 MB
  bf16* Whb = (bf16*)(ws + 2 * GI_ELEMS * sizeof(bf16));  // 12.6 MB
  bf16* h16 = Whb + 2 * 3145728;                          // 1 MB ping-pong
  unsigned* flags = (unsigned*)((char*)h16 + 1048576);    // 4 KB (8x512B)

  // bf16 X / Wi scratch lives in d_out (fully overwritten afterwards)
  bf16* Xb = (bf16*)d_out;
  bf16* Wib_f = Xb + 33554432;
  bf16* Wib_r = Wib_f + 3145728;

  hipMemsetAsync(h16, 0, 1048576 + 4096, stream);

  cvt_bf16<<<16384, 256, 0, stream>>>(x, Xb, 33554432);
  cvt_bf16<<<1536, 256, 0, stream>>>(Wi_f, Wib_f, 3145728);
  cvt_bf16<<<1536, 256, 0, stream>>>(Wi_r, Wib_r, 3145728);
  cvt_whb<<<3072, 256, 0, stream>>>(Wh_f, Wh_r, Whb);

  gi_gemm<<<dim3(24, 256), 256, 0, stream>>>(Xb, Wib_f, bi_f, Gi);
  gi_gemm<<<dim3(24, 256), 256, 0, stream>>>(Xb, Wib_r, bi_r, Gi + GI_ELEMS);

  gru_persist_s<<<dim3(32, 4, 2), 256, 0, stream>>>(Whb, bh_f, bh_r, Gi, mask,
                                                    h16, flags, out);
}